// Round 1
// baseline (165.856 us; speedup 1.0000x reference)
//
#include <hip/hip_runtime.h>

#define N_IMG 64
#define C_CH 3
#define H_IMG 64
#define W_IMG 64
#define NPIX (H_IMG * W_IMG)   // 4096
#define HO 58                  // H - 7 + 1
#define WO 58
#define DSTRIDE 68             // 64 + 4 pad: keeps float4 stores aligned, <=2-way LDS conflicts
#define HSTRIDE 59             // 58 + 1 pad

// One block = one image pair (i, j) for combination z:
//   z=0: xx (i<j only, symmetric), z=1: yy (i<j only), z=2: xy (all pairs)
// Pipeline: global->LDS diff-sq map -> horizontal 7-wide sliding sum ->
// vertical 7-wide sliding sum + exp + block reduce -> double atomicAdd.
__global__ __launch_bounds__(256) void patchmmd_pair_kernel(
    const float* __restrict__ x, const float* __restrict__ y,
    double* __restrict__ acc)
{
    const int i = blockIdx.x, j = blockIdx.y, z = blockIdx.z;
    if (z < 2 && i >= j) return;   // symmetric combos: upper triangle only

    const float* __restrict__ A = (z == 1) ? y : x;
    const float* __restrict__ B = (z == 0) ? x : y;

    __shared__ __align__(16) float D[H_IMG][DSTRIDE];   // 17.4 KB diff-sq map
    __shared__ float Hs[H_IMG][HSTRIDE];                // 15.1 KB horiz sums

    const float* a0 = A + (size_t)i * C_CH * NPIX;
    const float* b0 = B + (size_t)j * C_CH * NPIX;

    const int tid = threadIdx.x;

    // ---- Pass A: D[r][w] = sum_c (a-b)^2, float4-vectorized ----
    #pragma unroll
    for (int t = 0; t < 4; ++t) {
        const int v  = tid + t * 256;   // float4 index within plane, 0..1023
        const int px = v * 4;
        const int r  = px >> 6, w = px & 63;
        float4 d = make_float4(0.f, 0.f, 0.f, 0.f);
        #pragma unroll
        for (int c = 0; c < C_CH; ++c) {
            const float4 av = *reinterpret_cast<const float4*>(a0 + c * NPIX + px);
            const float4 bv = *reinterpret_cast<const float4*>(b0 + c * NPIX + px);
            const float dx = av.x - bv.x, dy = av.y - bv.y,
                        dz = av.z - bv.z, dw = av.w - bv.w;
            d.x += dx * dx; d.y += dy * dy; d.z += dz * dz; d.w += dw * dw;
        }
        *reinterpret_cast<float4*>(&D[r][w]) = d;
    }
    __syncthreads();

    // ---- Pass B: horizontal sliding sum of 7 -> Hs[r][c], c in [0,58) ----
    {
        const int r   = tid >> 2;        // 64 rows
        const int seg = tid & 3;         // 4 column segments: 15,15,15,13
        const int c0  = seg * 15;
        const int c1  = min(WO, c0 + 15);
        float s = 0.f;
        #pragma unroll
        for (int k = 0; k < 7; ++k) s += D[r][c0 + k];
        Hs[r][c0] = s;
        for (int c = c0 + 1; c < c1; ++c) {
            s += D[r][c + 6] - D[r][c - 1];
            Hs[r][c] = s;
        }
    }
    __syncthreads();

    // ---- Pass C: vertical sliding sum of 7, exp, accumulate ----
    float local = 0.f;
    if (tid < WO * 4) {                  // 232 active threads
        const int c   = tid % WO;
        const int seg = tid / WO;        // 4 row segments: 15,15,15,13
        const int r0  = seg * 15;
        const int r1  = min(HO, r0 + 15);
        const float NEG_INV_2S2 = -1.0f / 288.0f;   // -1/(2*sigma^2), sigma=12
        float s = 0.f;
        #pragma unroll
        for (int k = 0; k < 7; ++k) s += Hs[r0 + k][c];
        local += __expf(s * NEG_INV_2S2);
        for (int r = r0 + 1; r < r1; ++r) {
            s += Hs[r + 6][c] - Hs[r - 1][c];
            local += __expf(s * NEG_INV_2S2);
        }
    }

    // ---- Block reduction (wave64 shuffle, then cross-wave via LDS) ----
    #pragma unroll
    for (int off = 32; off > 0; off >>= 1)
        local += __shfl_down(local, off, 64);
    __shared__ float wsum[4];
    if ((tid & 63) == 0) wsum[tid >> 6] = local;
    __syncthreads();
    if (tid == 0) {
        const float tot = wsum[0] + wsum[1] + wsum[2] + wsum[3];
        atomicAdd(&acc[z], (double)(tot * (1.0f / (float)(HO * WO))));
    }
}

// acc[0]=sum_{i<j} Kxx, acc[1]=sum_{i<j} Kyy, acc[2]=sum_{all} Kxy
__global__ void patchmmd_combine_kernel(const double* __restrict__ acc,
                                        float* __restrict__ out)
{
    const double mean_xx = 2.0 * acc[0] / (64.0 * 63.0);
    const double mean_yy = 2.0 * acc[1] / (64.0 * 63.0);
    const double mean_xy = acc[2] / (64.0 * 64.0);
    out[0] = (float)(mean_xx - 2.0 * mean_xy + mean_yy);
}

extern "C" void kernel_launch(void* const* d_in, const int* in_sizes, int n_in,
                              void* d_out, int out_size, void* d_ws, size_t ws_size,
                              hipStream_t stream)
{
    const float* x = (const float*)d_in[0];
    const float* y = (const float*)d_in[1];
    float* out   = (float*)d_out;
    double* acc  = (double*)d_ws;

    hipMemsetAsync(acc, 0, 3 * sizeof(double), stream);  // ws is re-poisoned 0xAA

    dim3 grid(N_IMG, N_IMG, 3);
    patchmmd_pair_kernel<<<grid, 256, 0, stream>>>(x, y, acc);
    patchmmd_combine_kernel<<<1, 1, 0, stream>>>(acc, out);
}

// Round 5
// 150.628 us; speedup vs baseline: 1.1011x; 1.1011x over previous
//
#include <hip/hip_runtime.h>

#define NIMG 64
#define CH 3
#define HH 64
#define WW 64
#define PLANE (HH * WW)      // 4096
#define IMGSZ (CH * PLANE)   // 12288
#define HO 58                // 64 - 7 + 1
#define WO 58
#define NSLOT 64             // atomic spread slots per combination

// One WAVE = one 15-row (last: 13-row) output strip of one image pair.
// lane = column. Reads rows straight from L2 (coalesced: lane c -> +4B),
// vertical 7-sum as in-register sliding window, horizontal 7-sum via 4
// cross-lane shuffles. No LDS, no __syncthreads.
template <int NOUT>
__device__ __forceinline__ float strip_accum(const float* __restrict__ a,
                                             const float* __restrict__ b,
                                             int r0, int c)
{
    constexpr int NR = NOUT + 6;          // input rows needed by this strip
    float d[NR];                          // channel-summed squared diff per row
    #pragma unroll
    for (int k = 0; k < NR; ++k) {
        const int off = (r0 + k) * WW + c;
        float s = 0.f;
        #pragma unroll
        for (int ch = 0; ch < CH; ++ch) {
            const float av = a[ch * PLANE + off];
            const float bv = b[ch * PLANE + off];
            const float df = av - bv;
            s = fmaf(df, df, s);
        }
        d[k] = s;
    }

    const float NEG_INV_2S2 = -1.0f / 288.0f;   // -1/(2*sigma^2), sigma=12
    float V = d[0] + d[1] + d[2] + d[3] + d[4] + d[5] + d[6];  // vertical 7-sum
    float acc = 0.f;
    #pragma unroll
    for (int t = 0; t < NOUT; ++t) {
        if (t > 0) V += d[t + 6] - d[t - 1];     // slide the vertical window
        // horizontal 7-sum across lanes: s7[c] = sum_{k=0..6} V[c+k]
        const float t1 = V  + __shfl_down(V,  1, 64);   // v[c]+v[c+1]
        const float t2 = t1 + __shfl_down(t1, 2, 64);   // v[c..c+3]
        const float s7 = t2 + __shfl_down(t1, 4, 64)    // + v[c+4]+v[c+5]
                            + __shfl_down(V,  6, 64);   // + v[c+6]
        if (c < WO) acc += __expf(s7 * NEG_INV_2S2);
    }
    return acc;
}

// grid (64, 64, 3): z=0 xx (i<j only), z=1 yy (i<j only), z=2 xy (all pairs)
__global__ __launch_bounds__(256) void patchmmd_pair_kernel(
    const float* __restrict__ x, const float* __restrict__ y,
    double* __restrict__ acc)
{
    const int i = blockIdx.x, j = blockIdx.y, z = blockIdx.z;
    if (z < 2 && i >= j) return;              // symmetric combos: upper triangle

    const float* __restrict__ A = ((z == 1) ? y : x) + (size_t)i * IMGSZ;
    const float* __restrict__ B = ((z == 0) ? x : y) + (size_t)j * IMGSZ;

    const int w = threadIdx.x >> 6;           // strip index (wave id)
    const int c = threadIdx.x & 63;           // column = lane

    float local;
    if (w < 3) local = strip_accum<15>(A, B, 15 * w, c);
    else       local = strip_accum<13>(A, B, 45,     c);

    // wave-level reduce (64 lanes)
    #pragma unroll
    for (int off = 32; off; off >>= 1)
        local += __shfl_down(local, off, 64);

    if (c == 0) {
        const int slot = z * NSLOT + ((i ^ (j << 3) ^ w) & (NSLOT - 1));
        atomicAdd(&acc[slot], (double)local);   // f64: order-independent enough
    }
}

// acc[z*64..]: partial sums of exp over all outputs of combination z
__global__ void patchmmd_combine_kernel(const double* __restrict__ acc,
                                        float* __restrict__ out)
{
    double s[3] = {0.0, 0.0, 0.0};
    for (int z = 0; z < 3; ++z)
        for (int k = 0; k < NSLOT; ++k) s[z] += acc[z * NSLOT + k];
    const double inv_hw = 1.0 / (double)(HO * WO);
    const double mean_xx = 2.0 * s[0] * inv_hw / (64.0 * 63.0);
    const double mean_yy = 2.0 * s[1] * inv_hw / (64.0 * 63.0);
    const double mean_xy = s[2] * inv_hw / (64.0 * 64.0);
    out[0] = (float)(mean_xx - 2.0 * mean_xy + mean_yy);
}

extern "C" void kernel_launch(void* const* d_in, const int* in_sizes, int n_in,
                              void* d_out, int out_size, void* d_ws, size_t ws_size,
                              hipStream_t stream)
{
    const float* x = (const float*)d_in[0];
    const float* y = (const float*)d_in[1];
    float* out  = (float*)d_out;
    double* acc = (double*)d_ws;

    hipMemsetAsync(acc, 0, 3 * NSLOT * sizeof(double), stream);  // ws re-poisoned 0xAA

    dim3 grid(NIMG, NIMG, 3);
    patchmmd_pair_kernel<<<grid, 256, 0, stream>>>(x, y, acc);
    patchmmd_combine_kernel<<<1, 1, 0, stream>>>(acc, out);
}

// Round 9
// 148.380 us; speedup vs baseline: 1.1178x; 1.0151x over previous
//
#include <hip/hip_runtime.h>

#define NIMG 64
#define CH 3
#define HH 64
#define WW 64
#define PLANE (HH * WW)      // 4096
#define IMGSZ (CH * PLANE)   // 12288
#define HO 58                // 64 - 7 + 1
#define WO 58
#define NSLOT 64             // atomic spread slots per combination

// One WAVE = one 15-row (last: 13-row) output strip of one image pair.
// lane = column. R6 restructure: horizontal 7-sum is computed PER INPUT ROW
// directly off the freshly loaded diff-sq value (21 independent 3-deep
// shuffle trees, interleaved with the loads), so no shuffle chain depends
// on the serial vertical slide. Vertical 7-sum is then a pure-register
// sliding window. No LDS, no __syncthreads.
template <int NOUT>
__device__ __forceinline__ float strip_accum(const float* __restrict__ a,
                                             const float* __restrict__ b,
                                             int r0, int c)
{
    constexpr int NR = NOUT + 6;          // input rows needed by this strip
    float h[NR];                          // per-row horizontal 7-sums
    #pragma unroll
    for (int k = 0; k < NR; ++k) {
        const int off = (r0 + k) * WW + c;
        const float d0 = a[off]             - b[off];
        const float d1 = a[PLANE + off]     - b[PLANE + off];
        const float d2 = a[2 * PLANE + off] - b[2 * PLANE + off];
        float d = d0 * d0;
        d = fmaf(d1, d1, d);
        d = fmaf(d2, d2, d);
        // horizontal 7-sum across lanes, independent tree per row:
        const float t1 = d  + __shfl_down(d,  1, 64);   // d[c]+d[c+1]
        const float t2 = t1 + __shfl_down(t1, 2, 64);   // d[c..c+3]
        h[k] = t2 + __shfl_down(t1, 4, 64)              // + d[c+4]+d[c+5]
                  + __shfl_down(d,  6, 64);             // + d[c+6]
    }

    const float NEG_INV_2S2 = -1.0f / 288.0f;   // -1/(2*sigma^2), sigma=12
    float V = h[0] + h[1] + h[2] + h[3] + h[4] + h[5] + h[6];
    float acc = 0.f;
    if (c < WO) acc = __expf(V * NEG_INV_2S2);
    #pragma unroll
    for (int t = 1; t < NOUT; ++t) {
        V += h[t + 6] - h[t - 1];               // slide vertical window (VALU only)
        if (c < WO) acc += __expf(V * NEG_INV_2S2);
    }
    return acc;
}

// grid (64, 64, 3): z=0 xx (i<j only), z=1 yy (i<j only), z=2 xy (all pairs)
__global__ __launch_bounds__(256) void patchmmd_pair_kernel(
    const float* __restrict__ x, const float* __restrict__ y,
    double* __restrict__ acc)
{
    const int i = blockIdx.x, j = blockIdx.y, z = blockIdx.z;
    if (z < 2 && i >= j) return;              // symmetric combos: upper triangle

    const float* __restrict__ A = ((z == 1) ? y : x) + (size_t)i * IMGSZ;
    const float* __restrict__ B = ((z == 0) ? x : y) + (size_t)j * IMGSZ;

    const int w = threadIdx.x >> 6;           // strip index (wave id)
    const int c = threadIdx.x & 63;           // column = lane

    float local;
    if (w < 3) local = strip_accum<15>(A, B, 15 * w, c);
    else       local = strip_accum<13>(A, B, 45,     c);

    // wave-level reduce (64 lanes)
    #pragma unroll
    for (int off = 32; off; off >>= 1)
        local += __shfl_down(local, off, 64);

    if (c == 0) {
        const int slot = z * NSLOT + ((i ^ (j << 3) ^ w) & (NSLOT - 1));
        atomicAdd(&acc[slot], (double)local);   // f64: order-independent enough
    }
}

// acc[z*64..]: partial sums of exp over all outputs of combination z
__global__ void patchmmd_combine_kernel(const double* __restrict__ acc,
                                        float* __restrict__ out)
{
    double s[3] = {0.0, 0.0, 0.0};
    for (int z = 0; z < 3; ++z)
        for (int k = 0; k < NSLOT; ++k) s[z] += acc[z * NSLOT + k];
    const double inv_hw = 1.0 / (double)(HO * WO);
    const double mean_xx = 2.0 * s[0] * inv_hw / (64.0 * 63.0);
    const double mean_yy = 2.0 * s[1] * inv_hw / (64.0 * 63.0);
    const double mean_xy = s[2] * inv_hw / (64.0 * 64.0);
    out[0] = (float)(mean_xx - 2.0 * mean_xy + mean_yy);
}

extern "C" void kernel_launch(void* const* d_in, const int* in_sizes, int n_in,
                              void* d_out, int out_size, void* d_ws, size_t ws_size,
                              hipStream_t stream)
{
    const float* x = (const float*)d_in[0];
    const float* y = (const float*)d_in[1];
    float* out  = (float*)d_out;
    double* acc = (double*)d_ws;

    hipMemsetAsync(acc, 0, 3 * NSLOT * sizeof(double), stream);  // ws re-poisoned 0xAA

    dim3 grid(NIMG, NIMG, 3);
    patchmmd_pair_kernel<<<grid, 256, 0, stream>>>(x, y, acc);
    patchmmd_combine_kernel<<<1, 1, 0, stream>>>(acc, out);
}

// Round 12
// 96.310 us; speedup vs baseline: 1.7221x; 1.5407x over previous
//
#include <hip/hip_runtime.h>

#define NIMG 64
#define CH 3
#define WW 64
#define PLANE 4096           // 64*64
#define IMGSZ (CH * PLANE)   // 12288
#define HO 58                // 64 - 7 + 1
#define WO 58
#define NSLOT 64             // atomic spread slots per combination

#define DS 68                // D row stride (floats): 272B, 16B-aligned, bank-skewed
#define HS 68                // Hs row stride (floats). R11 fix: was 60 -> s=7's
                             // second float4 (cols 60..63) overflowed into
                             // Hs[r+1][0..3], racing with valid data. 68 holds
                             // all written cols 0..63 + pad in-row.
#define DOFF 0               // D  = lds[0 .. 64*DS)
#define HOFF (64 * DS)       // Hs = lds[HOFF .. HOFF + 64*HS)

// Block = one image pair. Three fully data-parallel passes through LDS —
// NO serial sliding chains across iterations, every LDS/global op within a
// thread is independent (R6 post-mortem: both prior designs were
// latency-bound at VALUBusy<19% due to long dependent chains + 40-VGPR
// serialization; this design exposes MLP everywhere).
//  A: diff-sq map D[64][64] via float4 loads (24 indep per thread)
//  B: horizontal 7-sum, 8-col segments: 4 indep b128 reads -> prefix/slide
//  C: vertical 7-sum, 8-row column segments: 14 indep b32 reads -> slide+exp
__global__ __launch_bounds__(256) void patchmmd_pair_kernel(
    const float* __restrict__ x, const float* __restrict__ y,
    double* __restrict__ acc)
{
    const int i = blockIdx.x, j = blockIdx.y, z = blockIdx.z;
    if (z < 2 && i >= j) return;             // symmetric combos: upper triangle

    const float* __restrict__ A = ((z == 1) ? y : x) + (size_t)i * IMGSZ;
    const float* __restrict__ B = ((z == 0) ? x : y) + (size_t)j * IMGSZ;

    __shared__ __align__(16) float lds[HOFF + 64 * HS + 16];

    const int tid = threadIdx.x;

    // ---- Pass A: D[r][c] = sum_c (a-b)^2 ----
    #pragma unroll
    for (int t = 0; t < 4; ++t) {
        const int v = tid + t * 256;         // quad id 0..1023
        const int r = v >> 4, q = v & 15;
        const int off = r * WW + q * 4;
        float4 d = make_float4(0.f, 0.f, 0.f, 0.f);
        #pragma unroll
        for (int ch = 0; ch < CH; ++ch) {
            const float4 av = *reinterpret_cast<const float4*>(A + ch * PLANE + off);
            const float4 bv = *reinterpret_cast<const float4*>(B + ch * PLANE + off);
            const float ex = av.x - bv.x, ey = av.y - bv.y,
                        ez = av.z - bv.z, ew = av.w - bv.w;
            d.x = fmaf(ex, ex, d.x); d.y = fmaf(ey, ey, d.y);
            d.z = fmaf(ez, ez, d.z); d.w = fmaf(ew, ew, d.w);
        }
        *reinterpret_cast<float4*>(&lds[DOFF + r * DS + q * 4]) = d;
    }
    __syncthreads();

    // ---- Pass B: Hs[r][c] = sum_{k=0..6} D[r][c+k], 8-col segments ----
    #pragma unroll
    for (int t = 0; t < 2; ++t) {
        const int v = tid + t * 256;         // 0..511
        const int r = v >> 3, s = v & 7;     // row, col-segment (cols 8s..8s+7)
        const float* src = &lds[DOFF + r * DS + s * 8];
        const float4 q0 = *reinterpret_cast<const float4*>(src);
        const float4 q1 = *reinterpret_cast<const float4*>(src + 4);
        const float4 q2 = *reinterpret_cast<const float4*>(src + 8);
        const float4 q3 = *reinterpret_cast<const float4*>(src + 12); // s=7: pad/garbage, outputs unused
        const float d0=q0.x,d1=q0.y,d2=q0.z,d3=q0.w, d4=q1.x,d5=q1.y,d6=q1.z,d7=q1.w,
                    d8=q2.x,d9=q2.y,d10=q2.z,d11=q2.w, d12=q3.x,d13=q3.y;
        float h0 = d0+d1+d2+d3+d4+d5+d6;
        const float h1 = h0 + d7  - d0;
        const float h2 = h1 + d8  - d1;
        const float h3 = h2 + d9  - d2;
        const float h4 = h3 + d10 - d3;
        const float h5 = h4 + d11 - d4;
        const float h6 = h5 + d12 - d5;
        const float h7 = h6 + d13 - d6;
        float* dst = &lds[HOFF + r * HS + s * 8];
        *reinterpret_cast<float4*>(dst)     = make_float4(h0, h1, h2, h3);
        *reinterpret_cast<float4*>(dst + 4) = make_float4(h4, h5, h6, h7);
    }
    __syncthreads();

    // ---- Pass C: vertical 7-sum + exp, 8-row column segments ----
    const float NEG_INV_2S2 = -1.0f / 288.0f;   // -1/(2*sigma^2), sigma=12
    float local = 0.f;
    #pragma unroll
    for (int t = 0; t < 2; ++t) {
        const int v = tid + t * 256;         // 0..511
        const int c = v & 63;                // column (valid < 58)
        const int g = v >> 6;                // row segment: outputs rows 8g..8g+7
        float hr[14];
        #pragma unroll
        for (int k = 0; k < 14; ++k) {
            const int rk = min(8 * g + k, 63);    // clamp: g=7 needs rows 56..63 only
            hr[k] = lds[HOFF + rk * HS + c];      // 14 independent b32 reads
        }
        float V = hr[0]+hr[1]+hr[2]+hr[3]+hr[4]+hr[5]+hr[6];
        #pragma unroll
        for (int jj = 0; jj < 8; ++jj) {
            if (jj > 0) V += hr[jj + 6] - hr[jj - 1];
            if ((8 * g + jj) < HO && c < WO)
                local += __expf(V * NEG_INV_2S2);
        }
    }

    // ---- Block reduction ----
    #pragma unroll
    for (int off = 32; off; off >>= 1)
        local += __shfl_down(local, off, 64);
    __syncthreads();                          // pass-C reads done before lds reuse
    if ((tid & 63) == 0) lds[tid >> 6] = local;
    __syncthreads();
    if (tid == 0) {
        const float tot = lds[0] + lds[1] + lds[2] + lds[3];
        const int slot = z * NSLOT + ((i ^ (j * 19)) & (NSLOT - 1));
        atomicAdd(&acc[slot], (double)tot);
    }
}

// acc[z*64..]: partial sums of exp over all outputs of combination z
__global__ void patchmmd_combine_kernel(const double* __restrict__ acc,
                                        float* __restrict__ out)
{
    double s[3] = {0.0, 0.0, 0.0};
    for (int z = 0; z < 3; ++z)
        for (int k = 0; k < NSLOT; ++k) s[z] += acc[z * NSLOT + k];
    const double inv_hw = 1.0 / (double)(HO * WO);
    const double mean_xx = 2.0 * s[0] * inv_hw / (64.0 * 63.0);
    const double mean_yy = 2.0 * s[1] * inv_hw / (64.0 * 63.0);
    const double mean_xy = s[2] * inv_hw / (64.0 * 64.0);
    out[0] = (float)(mean_xx - 2.0 * mean_xy + mean_yy);
}

extern "C" void kernel_launch(void* const* d_in, const int* in_sizes, int n_in,
                              void* d_out, int out_size, void* d_ws, size_t ws_size,
                              hipStream_t stream)
{
    const float* x = (const float*)d_in[0];
    const float* y = (const float*)d_in[1];
    float* out  = (float*)d_out;
    double* acc = (double*)d_ws;

    hipMemsetAsync(acc, 0, 3 * NSLOT * sizeof(double), stream);  // ws re-poisoned 0xAA

    dim3 grid(NIMG, NIMG, 3);
    patchmmd_pair_kernel<<<grid, 256, 0, stream>>>(x, y, acc);
    patchmmd_combine_kernel<<<1, 1, 0, stream>>>(acc, out);
}